// Round 14
// baseline (154.325 us; speedup 1.0000x reference)
//
#include <hip/hip_runtime.h>
#include <hip/hip_bf16.h>
#include <cstdint>

typedef __attribute__((ext_vector_type(4))) float f32x4;
typedef __attribute__((ext_vector_type(8))) short s16x8;
typedef __attribute__((ext_vector_type(4))) unsigned short u16x4;
typedef __attribute__((ext_vector_type(2))) unsigned int u32x2;
typedef unsigned short u16;
typedef unsigned int u32;
typedef unsigned long long u64;

__device__ __forceinline__ float b2f(u16 u){ u32 v = ((u32)u)<<16; return __builtin_bit_cast(float, v); }
__device__ __forceinline__ u16 f2b(float f){
  __hip_bfloat16 h = __float2bfloat16(f);     // hw v_cvt path (RNE)
  return __builtin_bit_cast(u16, h);
}

__device__ __forceinline__ void gld16(const void* g, void* l){
  __builtin_amdgcn_global_load_lds((const __attribute__((address_space(1))) void*)g,
                                   (__attribute__((address_space(3))) void*)l, 16, 0, 0);
}

__device__ __forceinline__ f32x4 mfma16(s16x8 a, s16x8 b, f32x4 c){
  return __builtin_amdgcn_mfma_f32_16x16x32_bf16(a, b, c, 0, 0, 0);
}

// workspace element offsets (u16 elements)
#define WS_XB   0u           // [4096][1024] bf16 x
#define WS_WQ   (4u<<20)
#define WS_WK   (5u<<20)
#define WS_WV   (6u<<20)
#define WS_WO   (7u<<20)
#define WS_Q    (8u<<20)     // (B,H,S,HD) bf16, RoPE'd, Q scaled by 0.125*log2(e)
#define WS_K    (12u<<20)    // (B,H,S,HD) bf16, RoPE'd
#define WS_VT   (16u<<20)    // [1024][4096] bf16  (V^T: rows h*64+hd, cols b*2048+s)
#define WS_AO   (20u<<20)    // (B,S,D) bf16 attention output

#define QSCALE 0.18033688f   // 0.125 * log2(e): QK^T result is in log2 domain

// ---------------- convert fp32 -> bf16 (x + 4 weights) ----------------
__global__ __launch_bounds__(256) void k_convert(const float* __restrict__ x,
    const float* __restrict__ wq, const float* __restrict__ wk,
    const float* __restrict__ wv, const float* __restrict__ wo,
    u16* __restrict__ ws){
  u32 idx = blockIdx.x*256u + threadIdx.x;   // f32x4 index; total 2M
  const float* src; u16* dst;
  if (idx < (1u<<20)) { src = x + (u64)idx*4u; dst = ws + WS_XB + (u64)idx*4u; }
  else {
    u32 widx = idx - (1u<<20);
    u32 wsel = widx >> 18;
    u32 off  = (widx & ((1u<<18)-1u)) * 4u;
    const float* sp = (wsel==0u)?wq:(wsel==1u)?wk:(wsel==2u)?wv:wo;
    src = sp + off; dst = ws + WS_WQ + (u64)wsel*(1u<<20) + off;
  }
  f32x4 v = *(const f32x4*)src;
  u16x4 o = { f2b(v[0]), f2b(v[1]), f2b(v[2]), f2b(v[3]) };
  *(u16x4*)dst = o;
}

// ---------------- GEMM: C[i][j] = sum_k A[i][k]*B[j][k] (both row-major, K=1024) -----
// BK=32, double-buffered, FRAGMENT-ORDERED LDS: 2 stages x {A 8KB | B 8KB} = 32KB
// -> 5 blocks/CU (20 waves/CU). Frag f (= rowblk*4 + m) at [f*1024, +1024), lane
// granule at +lane*16 (conflict-free reads, base + imm offset). Stage t+1 issued
// BEFORE compute of stage t, one barrier/step, 32 steps.
// pass 0: 768 blocks (seg0=Q, seg1=K -> LDS C-tile -> RoPE -> scatter; seg2 = V^T)
// pass 1: 256 blocks: out = AO @ WO^T -> fp32
__global__ __launch_bounds__(256,5) void k_gemm(u16* __restrict__ ws, float* __restrict__ out,
    const float* __restrict__ fc, const float* __restrict__ fs, int pass){
  __shared__ char sm[32768];   // 2 stages x 16KB; all 32KB reused as bf16 C tile (modes 0/1)
  const u32 tid = threadIdx.x;
  const u32 w = tid>>6, l = tid&63u, g = l>>4, li = l&15u;
  const u32 wr = w>>1, wc = w&1u;
  u32 bx = blockIdx.x;

  const u16 *Ap, *Bp; u32 arow0, brow0; int mode;
  if (pass == 0) {
    u32 seg = bx >> 8, b2 = bx & 255u;
    if (seg < 2u) {
      Ap = ws + WS_XB; Bp = ws + (seg ? WS_WK : WS_WQ);
      arow0 = (b2 >> 3) * 128u; brow0 = (b2 & 7u) * 128u; mode = (int)seg;   // 0=Q 1=K
    } else {
      Ap = ws + WS_WV; Bp = ws + WS_XB;
      arow0 = (b2 >> 5) * 128u; brow0 = (b2 & 31u) * 128u; mode = 2;         // V^T
    }
  } else {
    Ap = ws + WS_AO; Bp = ws + WS_WO;
    arow0 = (bx >> 3) * 128u; brow0 = (bx & 7u) * 128u; mode = 3;            // O proj
  }

  f32x4 acc[4][4];
  #pragma unroll
  for (u32 m=0;m<4;++m)
    #pragma unroll
    for (u32 n=0;n<4;++n) acc[m][n] = 0.0f;

  // fragment-ordered staging: this thread stages A-frags {w*2, w*2+1} and B-frags
  // {w*2, w*2+1}. Frag f granule (lane l) = M[tilerow = (f>>2)*64 + (f&3)*16 + (l&15)]
  //                                          [k0 + (l>>4)*8 .. +8]
  const u32 fA = w*2u;
  u32 frow[2];
  #pragma unroll
  for (u32 j=0;j<2u;++j){
    u32 f = fA + j;
    frow[j] = (f>>2)*64u + (f&3u)*16u + li;
  }
  const u32 fcol = g*8u;
  auto STAGE_G = [&](u32 s, u32 t){
    const u32 k0 = t*32u;
    #pragma unroll
    for (u32 j=0;j<2u;++j){
      u32 f = fA + j;
      gld16(Ap + (u64)(arow0 + frow[j])*1024u + k0 + fcol, sm + s*16384u + f*1024u);
      gld16(Bp + (u64)(brow0 + frow[j])*1024u + k0 + fcol, sm + s*16384u + 8192u + f*1024u);
    }
  };

  STAGE_G(0u, 0u);
  __syncthreads();

  u32 cur = 0u;
  for (u32 t = 0; t < 32u; ++t) {
    if (t + 1u < 32u) STAGE_G(cur^1u, t+1u);   // issue-early prefetch
    const char* kb = sm + cur*16384u + l*16u;  // fragment reads: base + imm offset
    s16x8 af[4], bf[4];
    #pragma unroll
    for (u32 m=0;m<4;++m) af[m] = *(const s16x8*)(kb + (wr*4u+m)*1024u);
    #pragma unroll
    for (u32 n=0;n<4;++n) bf[n] = *(const s16x8*)(kb + 8192u + (wc*4u+n)*1024u);
    #pragma unroll
    for (u32 m=0;m<4;++m)
      #pragma unroll
      for (u32 n=0;n<4;++n)
        acc[m][n] = mfma16(af[m], bf[n], acc[m][n]);
    __syncthreads();   // drains prefetch (issued before compute) + protects reuse
    cur ^= 1u;
  }

  u16* qdst = ws + WS_Q; u16* kdst = ws + WS_K; u16* vtd = ws + WS_VT;
  if (mode <= 1) {
    // stage C tile (128 rows x 128 cols bf16, 256B rows) in LDS, swizzled
    #pragma unroll
    for (u32 m=0;m<4;++m)
      #pragma unroll
      for (u32 n=0;n<4;++n)
        #pragma unroll
        for (u32 q=0;q<4;++q){
          u32 row = wr*64u + m*16u + 4u*g + q;
          u32 colb = (wc*64u + n*16u + li)*2u;
          *(u16*)(sm + row*256u + (colb ^ ((row&7u)<<4))) = f2b(acc[m][n][q]);
        }
    __syncthreads();
    // one thread = one row-half: RoPE pairs adjacent in-register, coalesced tables+stores
    u32 row = tid >> 1, half = tid & 1u;
    u32 r = arow0 + row;
    u32 b = r >> 11, s = r & 2047u;
    u32 h = (brow0 >> 6) + half;
    float qs = (mode==0) ? QSCALE : 1.0f;
    u16* d = ((mode==0) ? qdst : kdst) + (u64)(((b<<4)+h)*2048u + s)*64u;
    #pragma unroll
    for (u32 u0=0; u0<8u; ++u0){
      s16x8 cv = *(const s16x8*)(sm + row*256u + ((half*128u + u0*16u) ^ ((row&7u)<<4)));
      f32x4 cvv = *(const f32x4*)(fc + s*32u + u0*4u);
      f32x4 svv = *(const f32x4*)(fs + s*32u + u0*4u);
      s16x8 o;
      #pragma unroll
      for (u32 i=0;i<4;++i){
        float t0 = b2f((u16)cv[2*i]), t1 = b2f((u16)cv[2*i+1]);
        o[2*i]   = (short)f2b((t0*cvv[i] - t1*svv[i])*qs);
        o[2*i+1] = (short)f2b((t0*svv[i] + t1*cvv[i])*qs);
      }
      *(s16x8*)(d + u0*8u) = o;
    }
  } else {
    #pragma unroll
    for (u32 m=0;m<4;++m){
      u32 r0 = arow0 + wr*64u + m*16u + 4u*g;
      #pragma unroll
      for (u32 n=0;n<4;++n){
        u32 c = brow0 + wc*64u + n*16u + li;
        #pragma unroll
        for (u32 q=0;q<4;++q){
          float v = acc[m][n][q];
          u32 r = r0 + q;
          if (mode == 2) vtd[(u64)r*4096u + c] = f2b(v);
          else           out[(u64)r*1024u + c] = v;
        }
      }
    }
  }
}

// ---------------- Flash attention (causal), 4 waves x 16 q-rows, KVBLK=64 ----------------
// R13 (best-equal): swapped QK, fragment-ordered K/V staging, cvt_pk P-store,
// dbuf issue-early, grid 1024 LPT, 40KB LDS.
__global__ __launch_bounds__(256,4) void k_attn(u16* __restrict__ ws){
  __shared__ char sm[40960];  // 2 stages x {K 8KB | V 8KB} frag-ordered | P 4 x 2KB swz
  const u32 tid = threadIdx.x;
  const u32 w = tid>>6, l = tid&63u, g = l>>4, li = l&15u;
  u32 bx = blockIdx.x;
  u32 qt = 31u - (bx >> 5);     // heavy q-tiles dispatched first (LPT)
  u32 bh = bx & 31u;
  u32 b = bh >> 4, h = bh & 15u;
  const u16* Q  = ws + WS_Q + (u64)bh*2048u*64u;
  const u16* Kp = ws + WS_K + (u64)bh*2048u*64u;
  const u16* Vt = ws + WS_VT + (u64)(h*64u)*4096u + b*2048u;
  u16* AO = ws + WS_AO;
  const u32 qw = qt*64u + w*16u;

  // Q fragments (B-operand): lane holds Q[qw+li][kk*32 + g*8 + j]
  s16x8 qa[2];
  #pragma unroll
  for (u32 kk=0;kk<2;++kk)
    qa[kk] = *(const s16x8*)(Q + (u64)(qw + li)*64u + kk*32u + g*8u);

  s16x8 ones;
  #pragma unroll
  for (u32 i=0;i<8;++i) ones[i] = (short)0x3F80;   // bf16 1.0

  f32x4 o[4]; f32x4 lsum;
  #pragma unroll
  for (u32 n=0;n<4;++n) o[n] = 0.0f;
  lsum = 0.0f;

  char* pl = sm + 32768 + w*2048u;   // P: 16 rows x 128B, XOR-swizzled (li&7)<<4
  const u32 nt = qt + 1u;

  const u32 f0 = w*2u;
  u32 kof[2], vof[2];
  #pragma unroll
  for (u32 j=0;j<2u;++j){
    u32 f = f0 + j;
    kof[j] = ((f>>1)*16u + li)*64u  + (f&1u)*32u + g*8u;
    vof[j] = ((f>>1)*16u + li)*4096u + (f&1u)*32u + g*8u;
  }
  auto STAGE = [&](u32 s, u32 kvb){
    #pragma unroll
    for (u32 j=0;j<2u;++j){
      u32 f = f0 + j;
      gld16(Kp + (u64)kvb*64u + kof[j], sm + s*16384u + f*1024u);
      gld16(Vt + (u64)vof[j] + kvb,     sm + s*16384u + 8192u + f*1024u);
    }
  };

  STAGE(0u, 0u);
  __syncthreads();

  u32 cur = 0u;
  for (u32 t = 0; t < nt; ++t) {
    const u32 kvb = t*64u;
    if (t + 1u < nt) STAGE(cur^1u, kvb + 64u);   // issue-early prefetch
    const char* kb = sm + cur*16384u + l*16u;    // fragment reads: base + imm offset

    s16x8 kf[8];
    #pragma unroll
    for (u32 f=0; f<8u; ++f)
      kf[f] = *(const s16x8*)(kb + f*1024u);

    // swapped QK^T: sv[n][r] = S[kv = kvb + n*16 + 4g + r][q = qw + li]
    f32x4 sv[4];
    #pragma unroll
    for (u32 n=0;n<4;++n) sv[n] = 0.0f;
    #pragma unroll
    for (u32 n=0;n<4;++n)
      #pragma unroll
      for (u32 kk=0;kk<2u;++kk)
        sv[n] = mfma16(kf[n*2u+kk], qa[kk], sv[n]);

    if (t == nt - 1u) {   // only the last tile is causally partial
      #pragma unroll
      for (u32 n=0;n<4;++n)
        #pragma unroll
        for (u32 r=0;r<4;++r)
          if (kvb + n*16u + 4u*g + r > qw + li) sv[n][r] = -1e9f;
    }
    // p = exp2(s2); pack kv-contiguous pairs, 1 ds_write_b64 per n (row = li)
    #pragma unroll
    for (u32 n=0;n<4;++n){
      f32x4 p;
      #pragma unroll
      for (u32 r=0;r<4;++r) p[r] = exp2f(sv[n][r]);
      u32 w0, w1;
      asm("v_cvt_pk_bf16_f32 %0, %1, %2" : "=v"(w0) : "v"(p[0]), "v"(p[1]));
      asm("v_cvt_pk_bf16_f32 %0, %1, %2" : "=v"(w1) : "v"(p[2]), "v"(p[3]));
      u32x2 pw = { w0, w1 };
      *(u32x2*)(pl + li*128u + ((n*32u + g*8u) ^ ((li&7u)<<4))) = pw;
    }
    // PV + row-sum (ones-column MFMA); V frag f = n*2+kk
    #pragma unroll
    for (u32 kk=0;kk<2u;++kk){
      s16x8 pa = *(const s16x8*)(pl + li*128u + ((kk*64u + g*16u) ^ ((li&7u)<<4)));
      lsum = mfma16(pa, ones, lsum);
      #pragma unroll
      for (u32 n=0;n<4;++n){
        s16x8 vf = *(const s16x8*)(kb + 8192u + (n*2u+kk)*1024u);
        o[n] = mfma16(pa, vf, o[n]);
      }
    }
    __syncthreads();   // drains prefetch (issued before compute) + protects buffer reuse
    cur ^= 1u;
  }

  // epilogue: normalize by MFMA row sums, write (B,S,D) bf16. q = qw+4g+r, hd = n*16+li
  #pragma unroll
  for (u32 r=0;r<4;++r){
    float inv = 1.0f / lsum[r];
    u32 qr = qw + 4u*g + r;
    #pragma unroll
    for (u32 n=0;n<4;++n){
      u32 hd = n*16u + li;
      AO[((u64)(b*2048u + qr))*1024u + h*64u + hd] = f2b(o[n][r] * inv);
    }
  }
}

extern "C" void kernel_launch(void* const* d_in, const int* in_sizes, int n_in,
                              void* d_out, int out_size, void* d_ws, size_t ws_size,
                              hipStream_t stream) {
  const float* x  = (const float*)d_in[0];
  const float* fc = (const float*)d_in[1];
  const float* fs = (const float*)d_in[2];
  // d_in[3] = mask (unused; causal mask applied analytically)
  const float* wq = (const float*)d_in[4];
  const float* wk = (const float*)d_in[5];
  const float* wv = (const float*)d_in[6];
  const float* wo = (const float*)d_in[7];
  u16* ws = (u16*)d_ws;
  float* out = (float*)d_out;

  k_convert<<<8192, 256, 0, stream>>>(x, wq, wk, wv, wo, ws);
  k_gemm  <<<768,  256, 0, stream>>>(ws, out, fc, fs, 0);   // Q,K (RoPE fused), V^T
  k_attn  <<<1024, 256, 0, stream>>>(ws);                   // causal flash attention
  k_gemm  <<<256,  256, 0, stream>>>(ws, out, fc, fs, 1);   // output projection -> fp32
}

// Round 15
// 131.193 us; speedup vs baseline: 1.1763x; 1.1763x over previous
//
#include <hip/hip_runtime.h>
#include <hip/hip_bf16.h>
#include <cstdint>

typedef __attribute__((ext_vector_type(4))) float f32x4;
typedef __attribute__((ext_vector_type(8))) short s16x8;
typedef __attribute__((ext_vector_type(4))) unsigned short u16x4;
typedef __attribute__((ext_vector_type(2))) unsigned int u32x2;
typedef unsigned short u16;
typedef unsigned int u32;
typedef unsigned long long u64;

__device__ __forceinline__ float b2f(u16 u){ u32 v = ((u32)u)<<16; return __builtin_bit_cast(float, v); }
__device__ __forceinline__ u16 f2b(float f){
  __hip_bfloat16 h = __float2bfloat16(f);     // hw v_cvt path (RNE)
  return __builtin_bit_cast(u16, h);
}

__device__ __forceinline__ void gld16(const void* g, void* l){
  __builtin_amdgcn_global_load_lds((const __attribute__((address_space(1))) void*)g,
                                   (__attribute__((address_space(3))) void*)l, 16, 0, 0);
}

__device__ __forceinline__ f32x4 mfma16(s16x8 a, s16x8 b, f32x4 c){
  return __builtin_amdgcn_mfma_f32_16x16x32_bf16(a, b, c, 0, 0, 0);
}

// workspace element offsets (u16 elements)
#define WS_XB   0u           // [4096][1024] bf16 x
#define WS_WQ   (4u<<20)
#define WS_WK   (5u<<20)
#define WS_WV   (6u<<20)
#define WS_WO   (7u<<20)
#define WS_Q    (8u<<20)     // (B,H,S,HD) bf16, RoPE'd, Q scaled by 0.125*log2(e)
#define WS_K    (12u<<20)    // (B,H,S,HD) bf16, RoPE'd
#define WS_VT   (16u<<20)    // [1024][4096] bf16  (V^T: rows h*64+hd, cols b*2048+s)
#define WS_AO   (20u<<20)    // (B,S,D) bf16 attention output

#define QSCALE 0.18033688f   // 0.125 * log2(e): QK^T result is in log2 domain

// ---------------- convert fp32 -> bf16 (x + 4 weights) ----------------
__global__ __launch_bounds__(256) void k_convert(const float* __restrict__ x,
    const float* __restrict__ wq, const float* __restrict__ wk,
    const float* __restrict__ wv, const float* __restrict__ wo,
    u16* __restrict__ ws){
  u32 idx = blockIdx.x*256u + threadIdx.x;   // f32x4 index; total 2M
  const float* src; u16* dst;
  if (idx < (1u<<20)) { src = x + (u64)idx*4u; dst = ws + WS_XB + (u64)idx*4u; }
  else {
    u32 widx = idx - (1u<<20);
    u32 wsel = widx >> 18;
    u32 off  = (widx & ((1u<<18)-1u)) * 4u;
    const float* sp = (wsel==0u)?wq:(wsel==1u)?wk:(wsel==2u)?wv:wo;
    src = sp + off; dst = ws + WS_WQ + (u64)wsel*(1u<<20) + off;
  }
  f32x4 v = *(const f32x4*)src;
  u16x4 o = { f2b(v[0]), f2b(v[1]), f2b(v[2]), f2b(v[3]) };
  *(u16x4*)dst = o;
}

// ---------------- GEMM: C[i][j] = sum_k A[i][k]*B[j][k] (both row-major, K=1024) -----
// BK=32, FRAGMENT-ORDERED LDS, 3-stage pipeline with COUNTED vmcnt (T4): per step,
// STAGE(t+2) issued, compute(t), then s_waitcnt vmcnt(4) (waits t+1's loads ONLY;
// t+2's stay in flight across the raw s_barrier — never drain to 0 in the loop).
// Safety: every ds_read feeds an MFMA pre-barrier (compiler lgkmcnt-before-use);
// buffer t%3 is rewritten only at step t+1, after the barrier following its last read.
// pass 0: 768 blocks (seg0=Q, seg1=K -> LDS C-tile -> RoPE -> scatter; seg2 = V^T)
// pass 1: 256 blocks: out = AO @ WO^T -> fp32
__global__ __launch_bounds__(256,3) void k_gemm(u16* __restrict__ ws, float* __restrict__ out,
    const float* __restrict__ fc, const float* __restrict__ fs, int pass){
  __shared__ char sm[49152];   // 3 stages x {A 8KB | B 8KB}; reused as 32KB C tile
  const u32 tid = threadIdx.x;
  const u32 w = tid>>6, l = tid&63u, g = l>>4, li = l&15u;
  const u32 wr = w>>1, wc = w&1u;
  u32 bx = blockIdx.x;

  const u16 *Ap, *Bp; u32 arow0, brow0; int mode;
  if (pass == 0) {
    u32 seg = bx >> 8, b2 = bx & 255u;
    if (seg < 2u) {
      Ap = ws + WS_XB; Bp = ws + (seg ? WS_WK : WS_WQ);
      arow0 = (b2 >> 3) * 128u; brow0 = (b2 & 7u) * 128u; mode = (int)seg;   // 0=Q 1=K
    } else {
      Ap = ws + WS_WV; Bp = ws + WS_XB;
      arow0 = (b2 >> 5) * 128u; brow0 = (b2 & 31u) * 128u; mode = 2;         // V^T
    }
  } else {
    Ap = ws + WS_AO; Bp = ws + WS_WO;
    arow0 = (bx >> 3) * 128u; brow0 = (bx & 7u) * 128u; mode = 3;            // O proj
  }

  f32x4 acc[4][4];
  #pragma unroll
  for (u32 m=0;m<4;++m)
    #pragma unroll
    for (u32 n=0;n<4;++n) acc[m][n] = 0.0f;

  // fragment-ordered staging (R14-verified): this thread stages A-frags {2w,2w+1} and
  // B-frags {2w,2w+1}. Frag f granule (lane l) = M[(f>>2)*64 + (f&3)*16 + (l&15)]
  //                                               [k0 + (l>>4)*8 .. +8]
  const u32 fA = w*2u;
  u32 frow[2];
  #pragma unroll
  for (u32 j=0;j<2u;++j){
    u32 f = fA + j;
    frow[j] = (f>>2)*64u + (f&3u)*16u + li;
  }
  const u32 fcol = g*8u;
  auto STAGE_G = [&](u32 s, u32 t){
    const u32 k0 = t*32u;
    #pragma unroll
    for (u32 j=0;j<2u;++j){
      u32 f = fA + j;
      gld16(Ap + (u64)(arow0 + frow[j])*1024u + k0 + fcol, sm + s*16384u + f*1024u);
      gld16(Bp + (u64)(brow0 + frow[j])*1024u + k0 + fcol, sm + s*16384u + 8192u + f*1024u);
    }
  };

  // prologue: two stages in flight, wait for the first only
  STAGE_G(0u, 0u);
  STAGE_G(1u, 1u);
  asm volatile("s_waitcnt vmcnt(4)" ::: "memory");
  __builtin_amdgcn_s_barrier();
  __builtin_amdgcn_sched_barrier(0);

  u32 cur = 0u, nxt = 1u, nx2 = 2u;
  for (u32 t = 0; t < 32u; ++t) {
    if (t + 2u < 32u) STAGE_G(nx2, t + 2u);    // issue 2-steps-ahead prefetch
    const char* kb = sm + cur*16384u + l*16u;  // fragment reads: base + imm offset
    s16x8 af[4], bf[4];
    #pragma unroll
    for (u32 m=0;m<4;++m) af[m] = *(const s16x8*)(kb + (wr*4u+m)*1024u);
    #pragma unroll
    for (u32 n=0;n<4;++n) bf[n] = *(const s16x8*)(kb + 8192u + (wc*4u+n)*1024u);
    #pragma unroll
    for (u32 m=0;m<4;++m)
      #pragma unroll
      for (u32 n=0;n<4;++n)
        acc[m][n] = mfma16(af[m], bf[n], acc[m][n]);
    // counted wait: t+1's 4 loads must land; t+2's 4 stay in flight across the barrier
    if (t + 2u < 32u) asm volatile("s_waitcnt vmcnt(4)" ::: "memory");
    else              asm volatile("s_waitcnt vmcnt(0)" ::: "memory");
    __builtin_amdgcn_s_barrier();
    __builtin_amdgcn_sched_barrier(0);
    u32 tmp = cur; cur = nxt; nxt = nx2; nx2 = tmp;
  }
  __syncthreads();   // full drain before LDS reuse by epilogue

  u16* qdst = ws + WS_Q; u16* kdst = ws + WS_K; u16* vtd = ws + WS_VT;
  if (mode <= 1) {
    // stage C tile (128 rows x 128 cols bf16, 256B rows) in LDS, swizzled
    #pragma unroll
    for (u32 m=0;m<4;++m)
      #pragma unroll
      for (u32 n=0;n<4;++n)
        #pragma unroll
        for (u32 q=0;q<4;++q){
          u32 row = wr*64u + m*16u + 4u*g + q;
          u32 colb = (wc*64u + n*16u + li)*2u;
          *(u16*)(sm + row*256u + (colb ^ ((row&7u)<<4))) = f2b(acc[m][n][q]);
        }
    __syncthreads();
    // one thread = one row-half: RoPE pairs adjacent in-register, coalesced tables+stores
    u32 row = tid >> 1, half = tid & 1u;
    u32 r = arow0 + row;
    u32 b = r >> 11, s = r & 2047u;
    u32 h = (brow0 >> 6) + half;
    float qs = (mode==0) ? QSCALE : 1.0f;
    u16* d = ((mode==0) ? qdst : kdst) + (u64)(((b<<4)+h)*2048u + s)*64u;
    #pragma unroll
    for (u32 u0=0; u0<8u; ++u0){
      s16x8 cv = *(const s16x8*)(sm + row*256u + ((half*128u + u0*16u) ^ ((row&7u)<<4)));
      f32x4 cvv = *(const f32x4*)(fc + s*32u + u0*4u);
      f32x4 svv = *(const f32x4*)(fs + s*32u + u0*4u);
      s16x8 o;
      #pragma unroll
      for (u32 i=0;i<4;++i){
        float t0 = b2f((u16)cv[2*i]), t1 = b2f((u16)cv[2*i+1]);
        o[2*i]   = (short)f2b((t0*cvv[i] - t1*svv[i])*qs);
        o[2*i+1] = (short)f2b((t0*svv[i] + t1*cvv[i])*qs);
      }
      *(s16x8*)(d + u0*8u) = o;
    }
  } else {
    #pragma unroll
    for (u32 m=0;m<4;++m){
      u32 r0 = arow0 + wr*64u + m*16u + 4u*g;
      #pragma unroll
      for (u32 n=0;n<4;++n){
        u32 c = brow0 + wc*64u + n*16u + li;
        #pragma unroll
        for (u32 q=0;q<4;++q){
          float v = acc[m][n][q];
          u32 r = r0 + q;
          if (mode == 2) vtd[(u64)r*4096u + c] = f2b(v);
          else           out[(u64)r*1024u + c] = v;
        }
      }
    }
  }
}

// ---------------- Flash attention (causal), 4 waves x 16 q-rows, KVBLK=64 ----------------
// R13 (best-equal): swapped QK, fragment-ordered K/V staging, cvt_pk P-store,
// dbuf issue-early, grid 1024 LPT, 40KB LDS.
__global__ __launch_bounds__(256,4) void k_attn(u16* __restrict__ ws){
  __shared__ char sm[40960];  // 2 stages x {K 8KB | V 8KB} frag-ordered | P 4 x 2KB swz
  const u32 tid = threadIdx.x;
  const u32 w = tid>>6, l = tid&63u, g = l>>4, li = l&15u;
  u32 bx = blockIdx.x;
  u32 qt = 31u - (bx >> 5);     // heavy q-tiles dispatched first (LPT)
  u32 bh = bx & 31u;
  u32 b = bh >> 4, h = bh & 15u;
  const u16* Q  = ws + WS_Q + (u64)bh*2048u*64u;
  const u16* Kp = ws + WS_K + (u64)bh*2048u*64u;
  const u16* Vt = ws + WS_VT + (u64)(h*64u)*4096u + b*2048u;
  u16* AO = ws + WS_AO;
  const u32 qw = qt*64u + w*16u;

  // Q fragments (B-operand): lane holds Q[qw+li][kk*32 + g*8 + j]
  s16x8 qa[2];
  #pragma unroll
  for (u32 kk=0;kk<2;++kk)
    qa[kk] = *(const s16x8*)(Q + (u64)(qw + li)*64u + kk*32u + g*8u);

  s16x8 ones;
  #pragma unroll
  for (u32 i=0;i<8;++i) ones[i] = (short)0x3F80;   // bf16 1.0

  f32x4 o[4]; f32x4 lsum;
  #pragma unroll
  for (u32 n=0;n<4;++n) o[n] = 0.0f;
  lsum = 0.0f;

  char* pl = sm + 32768 + w*2048u;   // P: 16 rows x 128B, XOR-swizzled (li&7)<<4
  const u32 nt = qt + 1u;

  const u32 f0 = w*2u;
  u32 kof[2], vof[2];
  #pragma unroll
  for (u32 j=0;j<2u;++j){
    u32 f = f0 + j;
    kof[j] = ((f>>1)*16u + li)*64u  + (f&1u)*32u + g*8u;
    vof[j] = ((f>>1)*16u + li)*4096u + (f&1u)*32u + g*8u;
  }
  auto STAGE = [&](u32 s, u32 kvb){
    #pragma unroll
    for (u32 j=0;j<2u;++j){
      u32 f = f0 + j;
      gld16(Kp + (u64)kvb*64u + kof[j], sm + s*16384u + f*1024u);
      gld16(Vt + (u64)vof[j] + kvb,     sm + s*16384u + 8192u + f*1024u);
    }
  };

  STAGE(0u, 0u);
  __syncthreads();

  u32 cur = 0u;
  for (u32 t = 0; t < nt; ++t) {
    const u32 kvb = t*64u;
    if (t + 1u < nt) STAGE(cur^1u, kvb + 64u);   // issue-early prefetch
    const char* kb = sm + cur*16384u + l*16u;    // fragment reads: base + imm offset

    s16x8 kf[8];
    #pragma unroll
    for (u32 f=0; f<8u; ++f)
      kf[f] = *(const s16x8*)(kb + f*1024u);

    // swapped QK^T: sv[n][r] = S[kv = kvb + n*16 + 4g + r][q = qw + li]
    f32x4 sv[4];
    #pragma unroll
    for (u32 n=0;n<4;++n) sv[n] = 0.0f;
    #pragma unroll
    for (u32 n=0;n<4;++n)
      #pragma unroll
      for (u32 kk=0;kk<2u;++kk)
        sv[n] = mfma16(kf[n*2u+kk], qa[kk], sv[n]);

    if (t == nt - 1u) {   // only the last tile is causally partial
      #pragma unroll
      for (u32 n=0;n<4;++n)
        #pragma unroll
        for (u32 r=0;r<4;++r)
          if (kvb + n*16u + 4u*g + r > qw + li) sv[n][r] = -1e9f;
    }
    // p = exp2(s2); pack kv-contiguous pairs, 1 ds_write_b64 per n (row = li)
    #pragma unroll
    for (u32 n=0;n<4;++n){
      f32x4 p;
      #pragma unroll
      for (u32 r=0;r<4;++r) p[r] = exp2f(sv[n][r]);
      u32 w0, w1;
      asm("v_cvt_pk_bf16_f32 %0, %1, %2" : "=v"(w0) : "v"(p[0]), "v"(p[1]));
      asm("v_cvt_pk_bf16_f32 %0, %1, %2" : "=v"(w1) : "v"(p[2]), "v"(p[3]));
      u32x2 pw = { w0, w1 };
      *(u32x2*)(pl + li*128u + ((n*32u + g*8u) ^ ((li&7u)<<4))) = pw;
    }
    // PV + row-sum (ones-column MFMA); V frag f = n*2+kk
    #pragma unroll
    for (u32 kk=0;kk<2u;++kk){
      s16x8 pa = *(const s16x8*)(pl + li*128u + ((kk*64u + g*16u) ^ ((li&7u)<<4)));
      lsum = mfma16(pa, ones, lsum);
      #pragma unroll
      for (u32 n=0;n<4;++n){
        s16x8 vf = *(const s16x8*)(kb + 8192u + (n*2u+kk)*1024u);
        o[n] = mfma16(pa, vf, o[n]);
      }
    }
    __syncthreads();   // drains prefetch (issued before compute) + protects buffer reuse
    cur ^= 1u;
  }

  // epilogue: normalize by MFMA row sums, write (B,S,D) bf16. q = qw+4g+r, hd = n*16+li
  #pragma unroll
  for (u32 r=0;r<4;++r){
    float inv = 1.0f / lsum[r];
    u32 qr = qw + 4u*g + r;
    #pragma unroll
    for (u32 n=0;n<4;++n){
      u32 hd = n*16u + li;
      AO[((u64)(b*2048u + qr))*1024u + h*64u + hd] = f2b(o[n][r] * inv);
    }
  }
}

extern "C" void kernel_launch(void* const* d_in, const int* in_sizes, int n_in,
                              void* d_out, int out_size, void* d_ws, size_t ws_size,
                              hipStream_t stream) {
  const float* x  = (const float*)d_in[0];
  const float* fc = (const float*)d_in[1];
  const float* fs = (const float*)d_in[2];
  // d_in[3] = mask (unused; causal mask applied analytically)
  const float* wq = (const float*)d_in[4];
  const float* wk = (const float*)d_in[5];
  const float* wv = (const float*)d_in[6];
  const float* wo = (const float*)d_in[7];
  u16* ws = (u16*)d_ws;
  float* out = (float*)d_out;

  k_convert<<<8192, 256, 0, stream>>>(x, wq, wk, wv, wo, ws);
  k_gemm  <<<768,  256, 0, stream>>>(ws, out, fc, fs, 0);   // Q,K (RoPE fused), V^T
  k_attn  <<<1024, 256, 0, stream>>>(ws);                   // causal flash attention
  k_gemm  <<<256,  256, 0, stream>>>(ws, out, fc, fs, 1);   // output projection -> fp32
}